// Round 8
// baseline (63.048 us; speedup 1.0000x reference)
//
#include <hip/hip_runtime.h>

// Problem constants
#define N_  32
#define C_  32
#define H_  56
#define W_  56
#define O_  32
#define HP_ 58   // padded
#define WP_ 58
#define HW_ (H_*W_)          // 3136
#define CHW_ (C_*H_*W_)      // 100352
#define KK_ 9
#define CKK_ (C_*KK_)        // 288
#define WROWB_ 1152          // bytes per weight o-row (288 fp32)
#define WROWSTRIDE_ ((size_t)HW_ * CKK_ * 4)   // bytes between o-rows in global

// xT layout: [C][HP][WP][N] (zero padded border), bf16
#define XT_ELEMS ((size_t)C_*HP_*WP_*N_)

#define KP_   144   // k-pairs (288/2)
#define PSTR_ 36    // uints per kp-row: 32 n + 4 pad

typedef __bf16 bf16x8 __attribute__((ext_vector_type(8)));
typedef float  f32x4  __attribute__((ext_vector_type(4)));

__device__ __forceinline__ void gload_lds16(const void* g, void* l) {
    __builtin_amdgcn_global_load_lds(
        (const __attribute__((address_space(1))) unsigned int*)g,
        (__attribute__((address_space(3))) unsigned int*)l,
        16, 0, 0);
}

// -------- transpose + pad + bf16-convert:  x[N][C][H][W] -> xT[C][HP][WP][N] --------
__global__ __launch_bounds__(256) void xpose_kernel(const float* __restrict__ x,
                                                    __bf16* __restrict__ xT) {
    const int c = blockIdx.x;   // 0..31
    const int y = blockIdx.y;   // 0..57 (padded row)
    __shared__ float sbuf[32 * 57];   // [n][col], row stride 57
    const int tid = threadIdx.x;
    const bool interior = (y >= 1) && (y <= H_);
    if (interior) {
        for (int idx = tid; idx < N_ * W_; idx += 256) {
            int n = idx / W_;
            int col = idx - n * W_;
            sbuf[n * 57 + col] = x[((size_t)(n * C_ + c) * H_ + (y - 1)) * W_ + col];
        }
    }
    __syncthreads();
    __bf16* dst = xT + ((size_t)(c * HP_ + y)) * WP_ * N_;
    for (int idx = tid; idx < WP_ * N_; idx += 256) {
        int xx = idx >> 5;        // 0..57
        int n  = idx & 31;
        float v = 0.f;
        if (interior && xx >= 1 && xx <= W_) v = sbuf[n * 57 + (xx - 1)];
        dst[idx] = (__bf16)v;
    }
}

// -------- MFMA main --------
// Block = ONE position (h,w), 4 waves = (oh, nh) quadrants of C[n=32][o=32].
// Round-8 change: weight tile (32 o-rows x 1152 B, packed) is staged into LDS
// via global_load_lds width=16 (36 wave-instrs, 9 per wave) — in-flight bytes
// live in the vmcnt queue (~57 KB/block, 2 blocks/CU) instead of VGPRs
// (~288 B/wave before), breaking the latency cap on the 115.6 MB read-once
// weight stream. Col-XOR swizzle (col ^= (row&3)<<5, involution applied on
// per-lane SOURCE addr and on the ds_read addr) cuts 16-way -> 4-way conflicts.
__global__ __launch_bounds__(256) void lc2d_mfma(const float* __restrict__ wgt,
                                                 const __bf16* __restrict__ xT,
                                                 const float* __restrict__ bias,
                                                 float* __restrict__ out) {
    __shared__ __align__(16) float4 wlds4[2304];      // 36864 B weight tile
    __shared__ unsigned P2[KP_ * PSTR_];              // 20736 B im2col
    __shared__ __align__(16) float sbuf[32][33];      // 4224 B epilogue

    const int tid = threadIdx.x;

    // bijective XCD-chunk swizzle: 3136 blocks = 8 XCDs x 392 consecutive wg ids
    const int flat = blockIdx.x;
    const int wg = (flat & 7) * 392 + (flat >> 3);
    const int w = wg % 56;
    const int h = wg / 56;
    const int pos = h * W_ + w;

    const int wave = tid >> 6;       // 0..3
    const int lane = tid & 63;
    const int nh = wave & 1;         // n-half quadrant
    const int oh = wave >> 1;        // o-half quadrant
    const int q = lane >> 4;         // k-group 0..3
    const int r = lane & 15;         // o (B-frag) / n (A-frag) within tile

    // ---- stage weight tile via global_load_lds (9 instrs/wave, 1 KB each) ----
    {
        const char* wposb = (const char*)wgt + (size_t)pos * WROWB_;
        char* wldsb = (char*)wlds4;
        const unsigned lane16 = lane * 16;
        #pragma unroll
        for (int u = 0; u < 9; ++u) {
            const unsigned t = wave * 9 + u;
            const unsigned phys = t * 1024 + lane16;
            const unsigned row = phys / WROWB_;            // magic-mul
            const unsigned within = phys - row * WROWB_;
            const unsigned col = within ^ ((row & 3) << 5);
            gload_lds16(wposb + (size_t)row * WROWSTRIDE_ + col,
                        wldsb + t * 1024);
        }
    }

    // ---- build P2 (coalesced): task = kp*4 + g (g = n-oct), 576 tasks ----
    {
        const __bf16* xbase = xT + (h * WP_ + w) * N_;
        #pragma unroll
        for (int it = 0; it < 3; ++it) {
            const int task = it * 256 + tid;
            if (task < 576) {
                const int kp = task >> 2;
                const int g  = task & 3;
                const int k0 = 2 * kp, k1 = 2 * kp + 1;
                const int c0 = k0 / 9, ij0 = k0 - 9 * c0;
                const int i0 = ij0 / 3, j0 = ij0 - 3 * i0;
                const int c1 = k1 / 9, ij1 = k1 - 9 * c1;
                const int i1 = ij1 / 3, j1 = ij1 - 3 * i1;
                const int off0 = c0 * (HP_ * WP_ * N_) + i0 * (WP_ * N_) + j0 * N_;
                const int off1 = c1 * (HP_ * WP_ * N_) + i1 * (WP_ * N_) + j1 * N_;
                union { uint4 qv; ushort sv[8]; } ua, ub;
                ua.qv = *(const uint4*)(xbase + off0 + 8 * g);
                ub.qv = *(const uint4*)(xbase + off1 + 8 * g);
                unsigned o0[8];
                #pragma unroll
                for (int m = 0; m < 8; ++m)
                    o0[m] = (unsigned)ua.sv[m] | ((unsigned)ub.sv[m] << 16);
                unsigned* dst = &P2[kp * PSTR_ + 8 * g];
                *(uint4*)(dst)     = make_uint4(o0[0], o0[1], o0[2], o0[3]);
                *(uint4*)(dst + 4) = make_uint4(o0[4], o0[5], o0[6], o0[7]);
            }
        }
    }
    __syncthreads();   // drains vmcnt (gload_lds) + lgkmcnt (ds_writes)

    // ---- MFMA loop: wave quadrant (nh, oh), 9 k-steps, 1 MFMA/step ----
    const int orow = oh * 16 + r;
    const char* wrowb = (const char*)wlds4 + orow * WROWB_;
    const unsigned rmask = (orow & 3) << 5;
    const unsigned* pa = &P2[(4 * q) * PSTR_ + nh * 16 + r];

    f32x4 acc = {0.f, 0.f, 0.f, 0.f};

    #pragma unroll
    for (int s = 0; s < 9; ++s) {
        union { unsigned u[4]; bf16x8 v; } a0;
        #pragma unroll
        for (int d = 0; d < 4; ++d)
            a0.u[d] = pa[(16 * s + d) * PSTR_];
        const unsigned bo = ((unsigned)(128 * s + 32 * q)) ^ rmask;
        const float4 ba = *(const float4*)(wrowb + bo);
        const float4 bb = *(const float4*)(wrowb + bo + 16);
        bf16x8 bfB;
        bfB[0] = (__bf16)ba.x; bfB[1] = (__bf16)ba.y; bfB[2] = (__bf16)ba.z; bfB[3] = (__bf16)ba.w;
        bfB[4] = (__bf16)bb.x; bfB[5] = (__bf16)bb.y; bfB[6] = (__bf16)bb.z; bfB[7] = (__bf16)bb.w;
        acc = __builtin_amdgcn_mfma_f32_16x16x32_bf16(a0.v, bfB, acc, 0, 0, 0);
    }

    // stage C into LDS: n = nh*16 + q*4 + reg, o = oh*16 + r (layout verified r2)
    #pragma unroll
    for (int reg = 0; reg < 4; ++reg)
        sbuf[nh * 16 + q * 4 + reg][oh * 16 + r] = acc[reg];
    __syncthreads();

    // store: 4 scalar stores per thread; w-adjacent blocks on same XCD merge
    // lines in L2 writeback (w-major swizzle chunks).
    #pragma unroll
    for (int rr = 0; rr < 4; ++rr) {
        const int fl = rr * 256 + tid;   // 0..1023 -> (n,o)
        const int n = fl >> 5;
        const int o = fl & 31;
        out[(size_t)n * CHW_ + o * HW_ + pos] = sbuf[n][o] + bias[o * HW_ + pos];
    }
}

// -------- fallback (if workspace too small): thread per output, bounds-checked --------
__global__ __launch_bounds__(256) void lc2d_naive(const float* __restrict__ x,
                                                  const float* __restrict__ wgt,
                                                  const float* __restrict__ bias,
                                                  float* __restrict__ out) {
    int idx = blockIdx.x * 256 + threadIdx.x;
    const int total = N_ * O_ * H_ * W_;
    if (idx >= total) return;
    int w = idx % W_;
    int h = (idx / W_) % H_;
    int o = (idx / HW_) % O_;
    int n = idx / CHW_;
    const float* wp = wgt + ((size_t)((o * H_ + h) * W_ + w)) * CKK_;
    float s = 0.f;
    for (int c = 0; c < C_; ++c) {
        for (int i = 0; i < 3; ++i) {
            int yy = h + i - 1;
            if (yy < 0 || yy >= H_) continue;
            for (int j = 0; j < 3; ++j) {
                int xx = w + j - 1;
                if (xx < 0 || xx >= W_) continue;
                s = fmaf(wp[c * KK_ + i * 3 + j],
                         x[((size_t)(n * C_ + c) * H_ + yy) * W_ + xx], s);
            }
        }
    }
    out[idx] = s + bias[idx % CHW_];
}

extern "C" void kernel_launch(void* const* d_in, const int* in_sizes, int n_in,
                              void* d_out, int out_size, void* d_ws, size_t ws_size,
                              hipStream_t stream) {
    const float* x    = (const float*)d_in[0];
    const float* wgt  = (const float*)d_in[1];
    const float* bias = (const float*)d_in[2];
    float* out = (float*)d_out;

    const size_t need = XT_ELEMS * sizeof(__bf16);
    if (ws_size >= need) {
        __bf16* xT = (__bf16*)d_ws;
        hipLaunchKernelGGL(xpose_kernel, dim3(C_, HP_), dim3(256), 0, stream, x, xT);
        hipLaunchKernelGGL(lc2d_mfma, dim3(3136), dim3(256), 0, stream, wgt, xT, bias, out);
    } else {
        int total = N_ * O_ * H_ * W_;
        hipLaunchKernelGGL(lc2d_naive, dim3((total + 255) / 256), dim3(256), 0, stream,
                           x, wgt, bias, out);
    }
}

// Round 9
// 53.490 us; speedup vs baseline: 1.1787x; 1.1787x over previous
//
#include <hip/hip_runtime.h>

// Problem constants
#define N_  32
#define C_  32
#define H_  56
#define W_  56
#define O_  32
#define HP_ 58   // padded
#define WP_ 58
#define HW_ (H_*W_)          // 3136
#define CHW_ (C_*H_*W_)      // 100352
#define KK_ 9
#define CKK_ (C_*KK_)        // 288
#define WROWB_ 1152          // bytes per weight o-row (288 fp32)
#define WROWSTRIDE_ ((size_t)HW_ * CKK_ * 4)   // bytes between o-rows in global
#define WTILE_B 36864        // one position's weight tile in LDS

// xT layout: [C][HP][WP][N] (zero padded border), bf16
#define XT_ELEMS ((size_t)C_*HP_*WP_*N_)

#define KP_   144   // k-pairs (288/2)
#define PSTR_ 36    // uints per kp-row: 32 n + 4 pad

typedef __bf16 bf16x8 __attribute__((ext_vector_type(8)));
typedef float  f32x4  __attribute__((ext_vector_type(4)));

__device__ __forceinline__ void gload_lds16(const void* g, void* l) {
    __builtin_amdgcn_global_load_lds(
        (const __attribute__((address_space(1))) unsigned int*)g,
        (__attribute__((address_space(3))) unsigned int*)l,
        16, 0, 0);
}

// -------- transpose + pad + bf16-convert:  x[N][C][H][W] -> xT[C][HP][WP][N] --------
__global__ __launch_bounds__(256) void xpose_kernel(const float* __restrict__ x,
                                                    __bf16* __restrict__ xT) {
    const int c = blockIdx.x;   // 0..31
    const int y = blockIdx.y;   // 0..57 (padded row)
    __shared__ float sb[32 * 57];
    const int tid = threadIdx.x;
    const bool interior = (y >= 1) && (y <= H_);
    if (interior) {
        for (int idx = tid; idx < N_ * W_; idx += 256) {
            int n = idx / W_;
            int col = idx - n * W_;
            sb[n * 57 + col] = x[((size_t)(n * C_ + c) * H_ + (y - 1)) * W_ + col];
        }
    }
    __syncthreads();
    __bf16* dst = xT + ((size_t)(c * HP_ + y)) * WP_ * N_;
    for (int idx = tid; idx < WP_ * N_; idx += 256) {
        int xx = idx >> 5;
        int n  = idx & 31;
        float v = 0.f;
        if (interior && xx >= 1 && xx <= W_) v = sb[n * 57 + (xx - 1)];
        dst[idx] = (__bf16)v;
    }
}

// -------- MFMA main --------
// Block = 2 consecutive w positions at one h; 4 waves = (nh, oh) quadrants.
// Weight tile staged via global_load_lds into a FRAGMENT-MAJOR LDS layout:
//   LDS byte (4s+2half+oh)*1024 + q*256 + r*16  <=  global (o=oh*16+r, dword 32s+8q+4half)
// so each compute ds_read_b128 is 64 consecutive lane-ordered 16-B units
// (conflict-free), and B addresses are base + compile-time immediates.
// Pipeline: issue x-loads(p+1) THEN gload_lds(p+1) before compute(p); in-order
// vmcnt completion lets the pack wait only on x while W(p+1) stays in flight
// across compute(p)+pack+epilogue. Bias folded into acc init.
__global__ __launch_bounds__(256) void lc2d_mfma(const float* __restrict__ wgt,
                                                 const __bf16* __restrict__ xT,
                                                 const float* __restrict__ bias,
                                                 float* __restrict__ out) {
    __shared__ __align__(16) char wlds[2][WTILE_B];   // 73728 B, frag-major, dbuf
    __shared__ unsigned P2[KP_ * PSTR_];              // 20736 B im2col (per position)
    __shared__ __align__(16) float sbuf[32][34][2];   // 8704 B epilogue

    const int tid = threadIdx.x;

    // bijective XCD-chunk swizzle: 1568 blocks = 8 XCDs x 196 consecutive wg ids
    const int flat = blockIdx.x;
    const int wg = (flat & 7) * 196 + (flat >> 3);
    const int wt = wg % 28;          // w-tile of 2 (w-major => same-h tiles same XCD)
    const int h  = wg / 28;          // 0..55
    const int w0 = wt * 2;

    const int wave = tid >> 6;       // 0..3
    const int lane = tid & 63;
    const int nh = wave & 1;         // n-half quadrant
    const int oh = wave >> 1;        // o-half quadrant
    const int q = lane >> 4;         // k-group 0..3
    const int r = lane & 15;         // o (B-frag) / n (A-frag) within tile

    // ---- weight staging: 9 gload_lds per wave, frag-major dest ----
    const size_t srcLaneOff = (size_t)r * WROWSTRIDE_ + (size_t)(q * 32);
    const char* wgt_b = (const char*)wgt;
    auto stage_w = [&](int pos, int b) {
        const char* base = wgt_b + (size_t)pos * WROWB_ + srcLaneOff;
        char* dst = wlds[b];
        #pragma unroll
        for (int u = 0; u < 9; ++u) {
            const int t = wave * 9 + u;                 // t = 4s + 2half + oh
            gload_lds16(base + (size_t)(t & 1) * (16 * WROWSTRIDE_)
                             + (unsigned)((t >> 2) * 128 + ((t >> 1) & 1) * 16),
                        dst + t * 1024);
        }
    };

    // ---- x im2col loads (issue phase) + pack phase ----
    uint4 xra[3], xrb[3];
    auto xload = [&](int pidx) {
        const __bf16* xb = xT + (h * WP_ + w0 + pidx) * N_;
        #pragma unroll
        for (int it = 0; it < 3; ++it) {
            const int task = it * 256 + tid;
            if (it < 2 || task < 576) {
                const int kp = task >> 2;
                const int g  = task & 3;
                const int k0 = 2 * kp, k1 = 2 * kp + 1;
                const int c0 = k0 / 9, ij0 = k0 - 9 * c0;
                const int i0 = ij0 / 3, j0 = ij0 - 3 * i0;
                const int c1 = k1 / 9, ij1 = k1 - 9 * c1;
                const int i1 = ij1 / 3, j1 = ij1 - 3 * i1;
                const int off0 = c0 * (HP_ * WP_ * N_) + i0 * (WP_ * N_) + j0 * N_;
                const int off1 = c1 * (HP_ * WP_ * N_) + i1 * (WP_ * N_) + j1 * N_;
                xra[it] = *(const uint4*)(xb + off0 + 8 * g);
                xrb[it] = *(const uint4*)(xb + off1 + 8 * g);
            }
        }
    };
    auto pack_p2 = [&]() {
        #pragma unroll
        for (int it = 0; it < 3; ++it) {
            const int task = it * 256 + tid;
            if (it < 2 || task < 576) {
                const int kp = task >> 2;
                const int g  = task & 3;
                union { uint4 qv; ushort sv[8]; } ua, ub;
                ua.qv = xra[it];
                ub.qv = xrb[it];
                unsigned o0[8];
                #pragma unroll
                for (int m = 0; m < 8; ++m)
                    o0[m] = (unsigned)ua.sv[m] | ((unsigned)ub.sv[m] << 16);
                unsigned* dst = &P2[kp * PSTR_ + 8 * g];
                *(uint4*)(dst)     = make_uint4(o0[0], o0[1], o0[2], o0[3]);
                *(uint4*)(dst + 4) = make_uint4(o0[4], o0[5], o0[6], o0[7]);
            }
        }
    };

    // ---- compute one position's quadrant from frag-major W LDS + P2 ----
    const char* wq = (const char*)0;  // set per call
    auto compute = [&](int b, int pos) -> f32x4 {
        const char* wa = wlds[b] + (oh * 1024 + q * 256 + r * 16);
        const unsigned* pa = &P2[(4 * q) * PSTR_ + nh * 16 + r];
        const float bv = bias[(oh * 16 + r) * HW_ + pos];
        f32x4 acc = {bv, bv, bv, bv};
        #pragma unroll
        for (int s = 0; s < 9; ++s) {
            union { unsigned u[4]; bf16x8 v; } a0;
            #pragma unroll
            for (int d = 0; d < 4; ++d)
                a0.u[d] = pa[(16 * s + d) * PSTR_];
            const float4 ba = *(const float4*)(wa + s * 4096);
            const float4 bb = *(const float4*)(wa + s * 4096 + 2048);
            bf16x8 bfB;
            bfB[0] = (__bf16)ba.x; bfB[1] = (__bf16)ba.y; bfB[2] = (__bf16)ba.z; bfB[3] = (__bf16)ba.w;
            bfB[4] = (__bf16)bb.x; bfB[5] = (__bf16)bb.y; bfB[6] = (__bf16)bb.z; bfB[7] = (__bf16)bb.w;
            acc = __builtin_amdgcn_mfma_f32_16x16x32_bf16(a0.v, bfB, acc, 0, 0, 0);
        }
        (void)wq;
        return acc;
    };
    auto epilogue = [&](f32x4 acc, int pidx) {
        #pragma unroll
        for (int reg = 0; reg < 4; ++reg)
            sbuf[nh * 16 + q * 4 + reg][oh * 16 + r][pidx] = acc[reg];
    };

    const int pos0 = h * W_ + w0;

    // ---- prologue: x(0) then W(0); pack waits only x (older in FIFO) ----
    xload(0);
    stage_w(pos0, 0);
    pack_p2();
    __syncthreads();                  // W(0) staged + P2(0) written

    // ---- p = 0: prefetch position 1, compute 0 ----
    xload(1);
    stage_w(pos0 + 1, 1);
    __builtin_amdgcn_sched_barrier(0);    // keep prefetch issues ahead of compute
    f32x4 acc0 = compute(0, pos0);
    __syncthreads();                  // all waves done reading P2(0); drains W(1)
    pack_p2();                        // P2(1); waits only x(1) regs
    epilogue(acc0, 0);
    __syncthreads();                  // P2(1) + sbuf slot0 visible

    // ---- p = 1 ----
    f32x4 acc1 = compute(1, pos0 + 1);
    epilogue(acc1, 1);
    __syncthreads();

    // ---- store: float2 over {w0, w0+1} per (n,o) ----
    #pragma unroll
    for (int rr = 0; rr < 4; ++rr) {
        const int fl = rr * 256 + tid;   // 0..1023 -> (n,o)
        const int n = fl >> 5;
        const int o = fl & 31;
        const float2 v = *(const float2*)&sbuf[n][o][0];
        *(float2*)(out + (size_t)n * CHW_ + o * HW_ + pos0) = v;
    }
}

// -------- fallback (if workspace too small): thread per output, bounds-checked --------
__global__ __launch_bounds__(256) void lc2d_naive(const float* __restrict__ x,
                                                  const float* __restrict__ wgt,
                                                  const float* __restrict__ bias,
                                                  float* __restrict__ out) {
    int idx = blockIdx.x * 256 + threadIdx.x;
    const int total = N_ * O_ * H_ * W_;
    if (idx >= total) return;
    int w = idx % W_;
    int h = (idx / W_) % H_;
    int o = (idx / HW_) % O_;
    int n = idx / CHW_;
    const float* wp = wgt + ((size_t)((o * H_ + h) * W_ + w)) * CKK_;
    float s = 0.f;
    for (int c = 0; c < C_; ++c) {
        for (int i = 0; i < 3; ++i) {
            int yy = h + i - 1;
            if (yy < 0 || yy >= H_) continue;
            for (int j = 0; j < 3; ++j) {
                int xx = w + j - 1;
                if (xx < 0 || xx >= W_) continue;
                s = fmaf(wp[c * KK_ + i * 3 + j],
                         x[((size_t)(n * C_ + c) * H_ + yy) * W_ + xx], s);
            }
        }
    }
    out[idx] = s + bias[idx % CHW_];
}

extern "C" void kernel_launch(void* const* d_in, const int* in_sizes, int n_in,
                              void* d_out, int out_size, void* d_ws, size_t ws_size,
                              hipStream_t stream) {
    const float* x    = (const float*)d_in[0];
    const float* wgt  = (const float*)d_in[1];
    const float* bias = (const float*)d_in[2];
    float* out = (float*)d_out;

    const size_t need = XT_ELEMS * sizeof(__bf16);
    if (ws_size >= need) {
        __bf16* xT = (__bf16*)d_ws;
        hipLaunchKernelGGL(xpose_kernel, dim3(C_, HP_), dim3(256), 0, stream, x, xT);
        hipLaunchKernelGGL(lc2d_mfma, dim3(1568), dim3(256), 0, stream, wgt, xT, bias, out);
    } else {
        int total = N_ * O_ * H_ * W_;
        hipLaunchKernelGGL(lc2d_naive, dim3((total + 255) / 256), dim3(256), 0, stream,
                           x, wgt, bias, out);
    }
}